// Round 3
// baseline (251.169 us; speedup 1.0000x reference)
//
#include <hip/hip_runtime.h>
#include <hip/hip_bf16.h>
#include <math.h>

typedef __attribute__((ext_vector_type(4))) float f32x4;
typedef __attribute__((ext_vector_type(8))) __bf16 bf16x8;

#define HLEN 200
#define BATCH_MAX 1024

// ---------------------------------------------------------------------------
// prep kernel: build bf16 MFMA B-fragment tables for W1/Wr1 in workspace,
// compute Ssum = sum(embed_distance[0][:]), and zero the ticket counters.
// Fragment f = (nt*4+ks)*64+lane holds W[nt*16+(lane&15)][ks*32+(lane>>4)*8..+7].
// ---------------------------------------------------------------------------
__global__ __launch_bounds__(256)
void nais_prep(const float* __restrict__ W1, const float* __restrict__ Wr1,
               const float* __restrict__ emb_dist,
               __bf16* __restrict__ wfrag, float* __restrict__ Ssum,
               int* __restrict__ cnt)
{
  const int id = blockIdx.x * 256 + threadIdx.x;
  if (blockIdx.x < 16) {
    const float* W = (id < 2048) ? W1 : Wr1;
    const int f    = id & 2047;
    const int lane = f & 63;
    const int ks   = (f >> 6) & 3;
    const int nt   = f >> 8;
    const int n  = nt * 16 + (lane & 15);
    const int d0 = ks * 32 + (lane >> 4) * 8;
    const float* src = W + n * 128 + d0;
    bf16x8 p;
    #pragma unroll
    for (int e = 0; e < 8; ++e) p[e] = (__bf16)src[e];
    *(bf16x8*)&wfrag[(size_t)id * 8] = p;
  } else {
    if (threadIdx.x < 64) {
      float s = emb_dist[threadIdx.x] + emb_dist[threadIdx.x + 64];
      #pragma unroll
      for (int m = 32; m >= 1; m >>= 1) s += __shfl_xor(s, m);
      if (threadIdx.x == 0) Ssum[0] = s;
    }
    for (int k = threadIdx.x; k < BATCH_MAX; k += 256) cnt[k] = 0;
  }
}

// ---------------------------------------------------------------------------
// main kernel: grid = 2*B. Block = (batch row b, branch br).
//   bid 0..B-1    : item branch   (emb_hist gathers, HBM-heavy)
//   bid B..2B-1   : region branch (emb_region is L2-resident)
// 256 threads = 4 waves; wave wg handles M-tiles mt = wg, wg+4, ... over ALL
// 128 N-columns (acc[8]); W fragments come from a 32 KB LDS copy in
// conflict-free fragment order. Each emb_hist row is gathered by exactly ONE
// wave (no duplicate HBM traffic). LDS ~36 KB -> 4 blocks/CU = 16 waves/CU.
// The two branch blocks of a row combine via a device-scope atomic ticket.
// ---------------------------------------------------------------------------
__global__ __launch_bounds__(256, 4)
void nais_main(const int* __restrict__ history, const int* __restrict__ target,
               const int* __restrict__ hist_region, const int* __restrict__ tgt_region,
               const float* __restrict__ tgt_dist,
               const float* __restrict__ emb_hist, const float* __restrict__ emb_tgt,
               const float* __restrict__ emb_region,
               const float* __restrict__ b1, const float* __restrict__ w2,
               const float* __restrict__ br1, const float* __restrict__ wr2,
               const __bf16* __restrict__ wfrag, const float* __restrict__ SsumPtr,
               float* __restrict__ slots, int* __restrict__ cnt,
               float* __restrict__ out, int B)
{
  __shared__ __align__(16) __bf16 wlds[16384];   // 32 KB fragment table
  __shared__ __align__(16) float tvec[128];
  __shared__ float bw[256];                      // [0..127]=bias, [128..255]=w2
  __shared__ float a_arr[208];
  __shared__ float dl[208];
  __shared__ float red[4][2];

  const int tid  = threadIdx.x;
  const int lane = tid & 63;
  const int wg   = tid >> 6;
  const int r    = lane & 15;   // M-row (A) / N-col (B) within 16-tile
  const int g    = lane >> 4;   // k-group 0..3
  const int bid  = blockIdx.x;
  const int br   = (bid >= B) ? 1 : 0;
  const int b    = br ? (bid - B) : bid;

  const float* table  = br ? emb_region  : emb_hist;
  const int*   idxarr = br ? hist_region : history;

  // stage this branch's W fragment table into LDS (linear copy, layout kept)
  {
    const bf16x8* src = (const bf16x8*)(wfrag + (size_t)br * 16384);
    #pragma unroll
    for (int i = 0; i < 8; ++i)
      *(bf16x8*)&wlds[(i * 256 + tid) * 8] = src[i * 256 + tid];
  }
  if (tid < 128) {
    tvec[tid] = br ? emb_region[(long)tgt_region[b] * 128 + tid]
                   : emb_tgt[(long)target[b] * 128 + tid];
    bw[tid] = br ? br1[tid] : b1[tid];
  } else {
    bw[tid] = br ? wr2[tid - 128] : w2[tid - 128];
  }
  __syncthreads();

  for (int mt = wg; mt < 13; mt += 4) {
    const int h = mt * 16 + r;
    const bool valid = (h < HLEN);
    const int idx = valid ? idxarr[b * HLEN + h] : 0;
    const float* row = table + (long)idx * 128;

    f32x4 acc[8];
    #pragma unroll
    for (int j = 0; j < 8; ++j) acc[j] = (f32x4){0.f, 0.f, 0.f, 0.f};
    float dot = 0.f;

    #pragma unroll
    for (int ks = 0; ks < 4; ++ks) {
      const int d0 = ks * 32 + g * 8;
      f32x4 x0 = *(const f32x4*)(row + d0);
      f32x4 x1 = *(const f32x4*)(row + d0 + 4);
      f32x4 t0 = *(const f32x4*)(tvec + d0);
      f32x4 t1 = *(const f32x4*)(tvec + d0 + 4);
      f32x4 q0 = x0 * t0;
      f32x4 q1 = x1 * t1;
      dot += ((q0.x + q0.y) + (q0.z + q0.w)) + ((q1.x + q1.y) + (q1.z + q1.w));
      bf16x8 fv;
      fv[0] = (__bf16)q0.x; fv[1] = (__bf16)q0.y; fv[2] = (__bf16)q0.z; fv[3] = (__bf16)q0.w;
      fv[4] = (__bf16)q1.x; fv[5] = (__bf16)q1.y; fv[6] = (__bf16)q1.z; fv[7] = (__bf16)q1.w;
      #pragma unroll
      for (int nt = 0; nt < 8; ++nt) {
        bf16x8 bf = *(const bf16x8*)&wlds[((nt * 4 + ks) * 64 + lane) * 8];
        acc[nt] = __builtin_amdgcn_mfma_f32_16x16x32_bf16(fv, bf, acc[nt], 0, 0, 0);
      }
    }

    // dot(h_row, t): combine the 4 k-groups sharing row r
    float df = dot;
    df += __shfl_xor(df, 16);
    df += __shfl_xor(df, 32);
    if (g == 0 && valid) dl[h] = df;

    // a[m] = sum over all 128 cols of relu(Y+b)*w2 (full row, no partials)
    float s0 = 0.f, s1 = 0.f, s2 = 0.f, s3 = 0.f;
    #pragma unroll
    for (int nt = 0; nt < 8; ++nt) {
      const int n = nt * 16 + r;
      const float bias = bw[n], wv = bw[128 + n];
      s0 += fmaxf(acc[nt].x + bias, 0.f) * wv;
      s1 += fmaxf(acc[nt].y + bias, 0.f) * wv;
      s2 += fmaxf(acc[nt].z + bias, 0.f) * wv;
      s3 += fmaxf(acc[nt].w + bias, 0.f) * wv;
    }
    #pragma unroll
    for (int m = 1; m <= 8; m <<= 1) {
      s0 += __shfl_xor(s0, m); s1 += __shfl_xor(s1, m);
      s2 += __shfl_xor(s2, m); s3 += __shfl_xor(s3, m);
    }
    if (r == 0) {
      const int base = mt * 16 + g * 4;
      a_arr[base + 0] = s0; a_arr[base + 1] = s1;
      a_arr[base + 2] = s2; a_arr[base + 3] = s3;
    }
  }

  __syncthreads();
  // branch-local epilogue: e = mask*exp(a+dist); S = sum e; P = sum e*dot
  float e = 0.f, p = 0.f;
  if (tid < HLEN) {
    const float dv  = tgt_dist[b * HLEN + tid] * SsumPtr[0];
    const float msk = (history[b * HLEN + tid] != target[b]) ? 1.f : 0.f;
    e = msk * expf(a_arr[tid] + dv);
    p = e * dl[tid];
  }
  #pragma unroll
  for (int m = 1; m <= 32; m <<= 1) {
    e += __shfl_xor(e, m);
    p += __shfl_xor(p, m);
  }
  if (lane == 0) { red[wg][0] = e; red[wg][1] = p; }
  __syncthreads();
  if (tid == 0) {
    const float S = red[0][0] + red[1][0] + red[2][0] + red[3][0];
    const float P = red[0][1] + red[1][1] + red[2][1] + red[3][1];
    const float c = P / sqrtf(S);
    // last-arriver combines the two branches and applies sigmoid
    __hip_atomic_store(&slots[br * B + b], c, __ATOMIC_RELAXED, __HIP_MEMORY_SCOPE_AGENT);
    const int t = __hip_atomic_fetch_add(&cnt[b], 1, __ATOMIC_ACQ_REL, __HIP_MEMORY_SCOPE_AGENT);
    if (t == 1) {
      const float o = __hip_atomic_load(&slots[(1 - br) * B + b], __ATOMIC_RELAXED, __HIP_MEMORY_SCOPE_AGENT);
      out[b] = 1.f / (1.f + expf(-(c + o)));
      __hip_atomic_store(&cnt[b], 0, __ATOMIC_RELAXED, __HIP_MEMORY_SCOPE_AGENT);  // ready for next launch
    }
  }
}

extern "C" void kernel_launch(void* const* d_in, const int* in_sizes, int n_in,
                              void* d_out, int out_size, void* d_ws, size_t ws_size,
                              hipStream_t stream) {
  const int*   history     = (const int*)d_in[0];
  const int*   target      = (const int*)d_in[1];
  const int*   hist_region = (const int*)d_in[2];
  const int*   tgt_region  = (const int*)d_in[3];
  const float* tgt_dist    = (const float*)d_in[4];
  const float* emb_hist    = (const float*)d_in[5];
  const float* emb_tgt     = (const float*)d_in[6];
  const float* emb_region  = (const float*)d_in[7];
  const float* emb_dist    = (const float*)d_in[8];
  const float* W1  = (const float*)d_in[9];
  const float* b1  = (const float*)d_in[10];
  const float* w2  = (const float*)d_in[11];
  const float* Wr1 = (const float*)d_in[12];
  const float* br1 = (const float*)d_in[13];
  const float* wr2 = (const float*)d_in[14];
  float* out = (float*)d_out;

  // workspace layout
  __bf16* wfrag = (__bf16*)d_ws;                          // 65536 B
  float*  Sp    = (float*)((char*)d_ws + 65536);          // 4 B (pad to 16)
  float*  slots = (float*)((char*)d_ws + 65552);          // 2*B floats
  int*    cnt   = (int*)  ((char*)d_ws + 65552 + 8192);   // B ints

  const int B = in_sizes[1];       // 1024
  hipLaunchKernelGGL(nais_prep, dim3(17), dim3(256), 0, stream,
                     W1, Wr1, emb_dist, wfrag, Sp, cnt);
  hipLaunchKernelGGL(nais_main, dim3(2 * B), dim3(256), 0, stream,
                     history, target, hist_region, tgt_region, tgt_dist,
                     emb_hist, emb_tgt, emb_region,
                     b1, w2, br1, wr2, wfrag, Sp, slots, cnt, out, B);
}

// Round 4
// 96.140 us; speedup vs baseline: 2.6125x; 2.6125x over previous
//
#include <hip/hip_runtime.h>
#include <hip/hip_bf16.h>
#include <math.h>

typedef __attribute__((ext_vector_type(4))) float f32x4;
typedef __attribute__((ext_vector_type(8))) __bf16 bf16x8;

#define HLEN 200
#define BATCH_MAX 1024

// ---------------------------------------------------------------------------
// prep kernel: build bf16 MFMA B-fragment tables for W1/Wr1 in workspace,
// compute Ssum = sum(embed_distance[0][:]), zero the ticket counters.
// Fragment f = (nt*4+ks)*64+lane holds W[nt*16+(lane&15)][ks*32+(lane>>4)*8..+7].
// ---------------------------------------------------------------------------
__global__ __launch_bounds__(256)
void nais_prep(const float* __restrict__ W1, const float* __restrict__ Wr1,
               const float* __restrict__ emb_dist,
               __bf16* __restrict__ wfrag, float* __restrict__ Ssum,
               int* __restrict__ cnt)
{
  const int id = blockIdx.x * 256 + threadIdx.x;
  if (blockIdx.x < 16) {
    const float* W = (id < 2048) ? W1 : Wr1;
    const int f    = id & 2047;
    const int lane = f & 63;
    const int ks   = (f >> 6) & 3;
    const int nt   = f >> 8;
    const int n  = nt * 16 + (lane & 15);
    const int d0 = ks * 32 + (lane >> 4) * 8;
    const float* src = W + n * 128 + d0;
    bf16x8 p;
    #pragma unroll
    for (int e = 0; e < 8; ++e) p[e] = (__bf16)src[e];
    *(bf16x8*)&wfrag[(size_t)id * 8] = p;
  } else {
    if (threadIdx.x < 64) {
      float s = emb_dist[threadIdx.x] + emb_dist[threadIdx.x + 64];
      #pragma unroll
      for (int m = 32; m >= 1; m >>= 1) s += __shfl_xor(s, m);
      if (threadIdx.x == 0) Ssum[0] = s;
    }
    for (int k = threadIdx.x; k < BATCH_MAX; k += 256) cnt[k] = 0;
  }
}

// ---------------------------------------------------------------------------
// main kernel: grid = 2*B. Block = (batch row b, branch br); item blocks first.
// 4 waves per block; wave kh = K-quarter (32 of 128 dims).
//  - wave holds 8 W fragments (its K-slice, all 8 N-tiles) = 32 VGPRs: no
//    hoist/spill hazard (round-3 lesson: 128-VGPR fragment sets spill).
//  - each emb row's 512 B fetched exactly once (4 waves x 128 B quarters).
//  - partial Y combined pre-ReLU via 32 KB LDS exchange (contiguous 1 KB per
//    ds op -> conflict-free), 2 barriers/iter; wave kh reduces N-tiles
//    kh*2..kh*2+1, partials summed in the epilogue.
//  - idx/row prefetch one iteration deep hides gather latency under the
//    combine phase + barriers.
// Region blocks (emb_region is L2-resident) retire early; scheduler backfills
// CUs with item blocks. Branch results combine via device-scope ticket.
// ---------------------------------------------------------------------------
__global__ __launch_bounds__(256, 4)
void nais_main(const int* __restrict__ history, const int* __restrict__ target,
               const int* __restrict__ hist_region, const int* __restrict__ tgt_region,
               const float* __restrict__ tgt_dist,
               const float* __restrict__ emb_hist, const float* __restrict__ emb_tgt,
               const float* __restrict__ emb_region,
               const float* __restrict__ b1, const float* __restrict__ w2,
               const float* __restrict__ br1, const float* __restrict__ wr2,
               const __bf16* __restrict__ wfrag, const float* __restrict__ SsumPtr,
               float* __restrict__ slots, int* __restrict__ cnt,
               float* __restrict__ out, int B)
{
  __shared__ __align__(16) float accbuf[4 * 8 * 64 * 4];   // 32 KB: [kh][nt][lane]f32x4
  __shared__ float apart[4][208];
  __shared__ float dpart[4][208];
  __shared__ float red[4][2];

  const int tid  = threadIdx.x;
  const int lane = tid & 63;
  const int kh   = tid >> 6;    // wave id = K-quarter 0..3
  const int r    = lane & 15;   // A-row / B-col within 16-tile
  const int g    = lane >> 4;   // k-subgroup 0..3
  const int bid  = blockIdx.x;
  const int br   = (bid >= B) ? 1 : 0;
  const int b    = br ? (bid - B) : bid;

  const float* table  = br ? emb_region  : emb_hist;
  const int*   idxarr = br ? hist_region : history;
  const float* bsrc   = br ? br1 : b1;
  const float* wsrc   = br ? wr2 : w2;

  // this wave's 8 W fragments (K-slice kh, all N-tiles) -> 32 VGPRs
  bf16x8 wf[8];
  #pragma unroll
  for (int nt = 0; nt < 8; ++nt)
    wf[nt] = *(const bf16x8*)&wfrag[(size_t)br * 16384 + ((nt * 4 + kh) * 64 + lane) * 8];

  // bias/w2 for the 2 N-tiles this wave combines
  float bias[2], wv[2];
  #pragma unroll
  for (int j = 0; j < 2; ++j) {
    const int n = (kh * 2 + j) * 16 + r;
    bias[j] = bsrc[n];
    wv[j]   = wsrc[n];
  }

  // target vector slice for this lane's K-positions (register-resident)
  const long trow = br ? (long)tgt_region[b] : (long)target[b];
  const float* tbase = (br ? emb_region : emb_tgt) + trow * 128 + kh * 32 + g * 8;
  const f32x4 tq0 = *(const f32x4*)(tbase);
  const f32x4 tq1 = *(const f32x4*)(tbase + 4);

  // software pipeline: prefetch row quarter for mt=0
  int   idx0 = (r < HLEN) ? idxarr[b * HLEN + r] : 0;
  const float* r0 = table + (long)idx0 * 128 + kh * 32 + g * 8;
  f32x4 px0 = *(const f32x4*)r0;
  f32x4 px1 = *(const f32x4*)(r0 + 4);

  for (int mt = 0; mt < 13; ++mt) {
    const f32x4 x0 = px0, x1 = px1;
    if (mt < 12) {
      const int hn = (mt + 1) * 16 + r;
      const int idx_n = (hn < HLEN) ? idxarr[b * HLEN + hn] : 0;
      const float* rn = table + (long)idx_n * 128 + kh * 32 + g * 8;
      px0 = *(const f32x4*)rn;
      px1 = *(const f32x4*)(rn + 4);
    }

    const f32x4 q0 = x0 * tq0;
    const f32x4 q1 = x1 * tq1;
    float dot = ((q0.x + q0.y) + (q0.z + q0.w)) + ((q1.x + q1.y) + (q1.z + q1.w));
    bf16x8 fv;
    fv[0] = (__bf16)q0.x; fv[1] = (__bf16)q0.y; fv[2] = (__bf16)q0.z; fv[3] = (__bf16)q0.w;
    fv[4] = (__bf16)q1.x; fv[5] = (__bf16)q1.y; fv[6] = (__bf16)q1.z; fv[7] = (__bf16)q1.w;

    f32x4 acc[8];
    #pragma unroll
    for (int nt = 0; nt < 8; ++nt) {
      acc[nt] = (f32x4){0.f, 0.f, 0.f, 0.f};
      acc[nt] = __builtin_amdgcn_mfma_f32_16x16x32_bf16(fv, wf[nt], acc[nt], 0, 0, 0);
    }

    // partial dot (this K-quarter) for row h: sum over the 4 g-subgroups
    float df = dot;
    df += __shfl_xor(df, 16);
    df += __shfl_xor(df, 32);
    const int h = mt * 16 + r;
    if (g == 0 && h < HLEN) dpart[kh][h] = df;

    // exchange partial Y across K-quarter waves (contiguous per-op -> no conflicts)
    #pragma unroll
    for (int nt = 0; nt < 8; ++nt)
      ((f32x4*)accbuf)[(kh * 8 + nt) * 64 + lane] = acc[nt];
    __syncthreads();

    // combine this wave's 2 N-tiles over all 4 K-quarters, ReLU + w2 reduce
    float s0 = 0.f, s1 = 0.f, s2 = 0.f, s3 = 0.f;
    #pragma unroll
    for (int j = 0; j < 2; ++j) {
      const int nt = kh * 2 + j;
      f32x4 y = ((f32x4*)accbuf)[(0 * 8 + nt) * 64 + lane];
      y += ((f32x4*)accbuf)[(1 * 8 + nt) * 64 + lane];
      y += ((f32x4*)accbuf)[(2 * 8 + nt) * 64 + lane];
      y += ((f32x4*)accbuf)[(3 * 8 + nt) * 64 + lane];
      s0 += fmaxf(y.x + bias[j], 0.f) * wv[j];
      s1 += fmaxf(y.y + bias[j], 0.f) * wv[j];
      s2 += fmaxf(y.z + bias[j], 0.f) * wv[j];
      s3 += fmaxf(y.w + bias[j], 0.f) * wv[j];
    }
    #pragma unroll
    for (int m = 1; m <= 8; m <<= 1) {
      s0 += __shfl_xor(s0, m); s1 += __shfl_xor(s1, m);
      s2 += __shfl_xor(s2, m); s3 += __shfl_xor(s3, m);
    }
    if (r == 0) {
      const int base = mt * 16 + g * 4;
      apart[kh][base + 0] = s0; apart[kh][base + 1] = s1;
      apart[kh][base + 2] = s2; apart[kh][base + 3] = s3;
    }
    __syncthreads();   // accbuf consumed; safe to overwrite next iteration
  }

  // branch-local epilogue: e = mask*exp(a+dist); S = sum e; P = sum e*dot
  float e = 0.f, p = 0.f;
  if (tid < HLEN) {
    const float dv  = tgt_dist[b * HLEN + tid] * SsumPtr[0];
    const float msk = (history[b * HLEN + tid] != target[b]) ? 1.f : 0.f;
    const float av = apart[0][tid] + apart[1][tid] + apart[2][tid] + apart[3][tid];
    const float dvl = dpart[0][tid] + dpart[1][tid] + dpart[2][tid] + dpart[3][tid];
    e = msk * expf(av + dv);
    p = e * dvl;
  }
  #pragma unroll
  for (int m = 1; m <= 32; m <<= 1) {
    e += __shfl_xor(e, m);
    p += __shfl_xor(p, m);
  }
  if (lane == 0) { red[kh][0] = e; red[kh][1] = p; }
  __syncthreads();
  if (tid == 0) {
    const float S = red[0][0] + red[1][0] + red[2][0] + red[3][0];
    const float P = red[0][1] + red[1][1] + red[2][1] + red[3][1];
    const float c = P / sqrtf(S);
    // last-arriver combines the two branches and applies sigmoid
    __hip_atomic_store(&slots[br * B + b], c, __ATOMIC_RELAXED, __HIP_MEMORY_SCOPE_AGENT);
    const int t = __hip_atomic_fetch_add(&cnt[b], 1, __ATOMIC_ACQ_REL, __HIP_MEMORY_SCOPE_AGENT);
    if (t == 1) {
      const float o = __hip_atomic_load(&slots[(1 - br) * B + b], __ATOMIC_RELAXED, __HIP_MEMORY_SCOPE_AGENT);
      out[b] = 1.f / (1.f + expf(-(c + o)));
      __hip_atomic_store(&cnt[b], 0, __ATOMIC_RELAXED, __HIP_MEMORY_SCOPE_AGENT);  // ready for next launch
    }
  }
}

extern "C" void kernel_launch(void* const* d_in, const int* in_sizes, int n_in,
                              void* d_out, int out_size, void* d_ws, size_t ws_size,
                              hipStream_t stream) {
  const int*   history     = (const int*)d_in[0];
  const int*   target      = (const int*)d_in[1];
  const int*   hist_region = (const int*)d_in[2];
  const int*   tgt_region  = (const int*)d_in[3];
  const float* tgt_dist    = (const float*)d_in[4];
  const float* emb_hist    = (const float*)d_in[5];
  const float* emb_tgt     = (const float*)d_in[6];
  const float* emb_region  = (const float*)d_in[7];
  const float* emb_dist    = (const float*)d_in[8];
  const float* W1  = (const float*)d_in[9];
  const float* b1  = (const float*)d_in[10];
  const float* w2  = (const float*)d_in[11];
  const float* Wr1 = (const float*)d_in[12];
  const float* br1 = (const float*)d_in[13];
  const float* wr2 = (const float*)d_in[14];
  float* out = (float*)d_out;

  // workspace layout
  __bf16* wfrag = (__bf16*)d_ws;                          // 65536 B
  float*  Sp    = (float*)((char*)d_ws + 65536);          // 4 B (pad to 16)
  float*  slots = (float*)((char*)d_ws + 65552);          // 2*B floats
  int*    cnt   = (int*)  ((char*)d_ws + 65552 + 8192);   // B ints

  const int B = in_sizes[1];       // 1024
  hipLaunchKernelGGL(nais_prep, dim3(17), dim3(256), 0, stream,
                     W1, Wr1, emb_dist, wfrag, Sp, cnt);
  hipLaunchKernelGGL(nais_main, dim3(2 * B), dim3(256), 0, stream,
                     history, target, hist_region, tgt_region, tgt_dist,
                     emb_hist, emb_tgt, emb_region,
                     b1, w2, br1, wr2, wfrag, Sp, slots, cnt, out, B);
}

// Round 5
// 93.941 us; speedup vs baseline: 2.6737x; 1.0234x over previous
//
#include <hip/hip_runtime.h>
#include <hip/hip_bf16.h>
#include <math.h>

typedef __attribute__((ext_vector_type(4))) float f32x4;
typedef __attribute__((ext_vector_type(8))) __bf16 bf16x8;

#define HLEN 200
#define BATCH_MAX 1024

// ---------------------------------------------------------------------------
// prep kernel: Ssum = sum(embed_distance[0][:]); zero the ticket counters.
// (W fragments are now staged per-block in the main kernel, folded with t.)
// ---------------------------------------------------------------------------
__global__ __launch_bounds__(256)
void nais_prep(const float* __restrict__ emb_dist, float* __restrict__ Ssum,
               int* __restrict__ cnt)
{
  const int tid = threadIdx.x;
  if (tid < 64) {
    float s = emb_dist[tid] + emb_dist[tid + 64];
    #pragma unroll
    for (int m = 32; m >= 1; m >>= 1) s += __shfl_xor(s, m);
    if (tid == 0) Ssum[0] = s;
  }
  for (int k = tid; k < BATCH_MAX; k += 256) cnt[k] = 0;
}

// ---------------------------------------------------------------------------
// main kernel: grid = 2*B. Block = (batch row b, branch br); item blocks first.
// 4 waves; wave wg owns M-tiles mt = wg, wg+4, ... with FULL N=128 (acc[8]).
//  - NO barriers / NO cross-wave exchange in the loop: prefetch (px, 1 tile
//    deep; idx 2 deep) stays in flight across iterations (round-4 lesson:
//    __syncthreads drains vmcnt(0) and kills pipelining).
//  - W' = bf16(W[n][d] * t[d]) staged once per block into LDS in MFMA
//    B-fragment order (t is block-uniform, so the x*t multiply disappears
//    from the inner loop). Single bf16 rounding of the product.
//  - all in-loop LDS reads go through an opaque zoff register
//    (asm "+v") so LICM cannot hoist the 32 fragment reads into VGPRs
//    (round-3 spill lesson).
//  - each emb row's 512 B gathered by exactly one wave (4 g-lanes take
//    disjoint 128 B quarters): no duplicate traffic.
// Region blocks (emb_region L2-resident) retire fast; ticket combine.
// ---------------------------------------------------------------------------
__global__ __launch_bounds__(256, 4)
void nais_main(const int* __restrict__ history, const int* __restrict__ target,
               const int* __restrict__ hist_region, const int* __restrict__ tgt_region,
               const float* __restrict__ tgt_dist,
               const float* __restrict__ emb_hist, const float* __restrict__ emb_tgt,
               const float* __restrict__ emb_region,
               const float* __restrict__ W1, const float* __restrict__ b1,
               const float* __restrict__ w2,
               const float* __restrict__ Wr1, const float* __restrict__ br1,
               const float* __restrict__ wr2,
               const float* __restrict__ SsumPtr,
               float* __restrict__ slots, int* __restrict__ cnt,
               float* __restrict__ out, int B)
{
  __shared__ __align__(16) __bf16 wlds[16384];   // 32 KB W' fragment table
  __shared__ __align__(16) float tvec[128];
  __shared__ __align__(8)  float bw2[256];       // interleaved {bias,w2} pairs
  __shared__ float a_arr[208];
  __shared__ float dl[208];
  __shared__ float red[4][2];

  const int tid  = threadIdx.x;
  const int lane = tid & 63;
  const int wg   = tid >> 6;
  const int r    = lane & 15;   // A-row / B-col within 16-tile
  const int g    = lane >> 4;   // k-subgroup 0..3
  const int bid  = blockIdx.x;
  const int br   = (bid >= B) ? 1 : 0;
  const int b    = br ? (bid - B) : bid;

  const float* table  = br ? emb_region  : emb_hist;
  const int*   idxarr = br ? hist_region : history;

  // phase 0: t-vector + interleaved bias/w2 into LDS
  if (tid < 128) {
    const long trow = br ? (long)tgt_region[b] : (long)target[b];
    tvec[tid] = (br ? emb_region : emb_tgt)[trow * 128 + tid];
    bw2[tid * 2]     = (br ? br1 : b1)[tid];
    bw2[tid * 2 + 1] = (br ? wr2 : w2)[tid];
  }

  // preload first tile (mt = wg) + idx for tile wg+4; in flight during staging
  int idx0;
  {
    const int h0 = wg * 16 + r;
    idx0 = (h0 < HLEN) ? idxarr[b * HLEN + h0] : 0;
  }
  f32x4 px[8];
  {
    const float* rowp = table + (long)idx0 * 128 + g * 8;
    #pragma unroll
    for (int ks = 0; ks < 4; ++ks) {
      px[2 * ks]     = *(const f32x4*)(rowp + ks * 32);
      px[2 * ks + 1] = *(const f32x4*)(rowp + ks * 32 + 4);
    }
  }
  int idxn;
  {
    const int hn = (wg + 4) * 16 + r;   // wg+4 <= 7 < 13, hn <= 127 < HLEN
    idxn = idxarr[b * HLEN + hn];
  }
  __syncthreads();   // tvec ready

  // phase 1: stage W' = bf16(W * t) fragments (8 per thread)
  {
    const float* Wsrc = br ? Wr1 : W1;
    #pragma unroll
    for (int ii = 0; ii < 8; ++ii) {
      const int f  = ii * 256 + tid;
      const int fl = f & 63;
      const int ks = (f >> 6) & 3;
      const int nt = f >> 8;
      const int n  = nt * 16 + (fl & 15);
      const int d0 = ks * 32 + (fl >> 4) * 8;
      const float* src = Wsrc + n * 128 + d0;
      f32x4 a0 = *(const f32x4*)src;
      f32x4 a1 = *(const f32x4*)(src + 4);
      const f32x4 t0 = *(const f32x4*)&tvec[d0];
      const f32x4 t1 = *(const f32x4*)&tvec[d0 + 4];
      a0 *= t0; a1 *= t1;
      bf16x8 p;
      p[0] = (__bf16)a0.x; p[1] = (__bf16)a0.y; p[2] = (__bf16)a0.z; p[3] = (__bf16)a0.w;
      p[4] = (__bf16)a1.x; p[5] = (__bf16)a1.y; p[6] = (__bf16)a1.z; p[7] = (__bf16)a1.w;
      *(bf16x8*)&wlds[(size_t)f * 8] = p;
    }
  }
  __syncthreads();   // W' table ready — LAST barrier before epilogue

  #pragma unroll 1
  for (int mt = wg; mt < 13; mt += 4) {
    // opaque zero offset: makes every in-loop LDS address loop-variant so
    // LICM cannot hoist the fragment reads into (spilling) registers
    unsigned zoff = 0;
    asm volatile("" : "+v"(zoff));
    const bf16x8* wb = (const bf16x8*)wlds + zoff;
    const f32x4*  tb = (const f32x4*)tvec + zoff;
    const float*  pb = (const float*)bw2 + zoff;

    // f32 dot(x, t) + bf16 A-fragments from the prefetched row
    float dot = 0.f;
    bf16x8 fvs[4];
    #pragma unroll
    for (int ks = 0; ks < 4; ++ks) {
      const f32x4 x0 = px[2 * ks], x1 = px[2 * ks + 1];
      const f32x4 t0 = tb[ks * 8 + g * 2];
      const f32x4 t1 = tb[ks * 8 + g * 2 + 1];
      const f32x4 q0 = x0 * t0;
      const f32x4 q1 = x1 * t1;
      dot += ((q0.x + q0.y) + (q0.z + q0.w)) + ((q1.x + q1.y) + (q1.z + q1.w));
      bf16x8 fv;
      fv[0] = (__bf16)x0.x; fv[1] = (__bf16)x0.y; fv[2] = (__bf16)x0.z; fv[3] = (__bf16)x0.w;
      fv[4] = (__bf16)x1.x; fv[5] = (__bf16)x1.y; fv[6] = (__bf16)x1.z; fv[7] = (__bf16)x1.w;
      fvs[ks] = fv;
    }

    // px is dead: issue next tile's gather (mt+4, via idxn) + idx for mt+8
    {
      const float* rowp = table + (long)idxn * 128 + g * 8;
      #pragma unroll
      for (int ks = 0; ks < 4; ++ks) {
        px[2 * ks]     = *(const f32x4*)(rowp + ks * 32);
        px[2 * ks + 1] = *(const f32x4*)(rowp + ks * 32 + 4);
      }
      const int tn = mt + 8;
      const int hn = tn * 16 + r;
      idxn = (tn < 13 && hn < HLEN) ? idxarr[b * HLEN + hn] : 0;
    }

    // GEMM tile: 32 MFMA, B-fragments from LDS (conflict-free layout)
    f32x4 acc[8];
    #pragma unroll
    for (int nt = 0; nt < 8; ++nt) acc[nt] = (f32x4){0.f, 0.f, 0.f, 0.f};
    #pragma unroll
    for (int ks = 0; ks < 4; ++ks) {
      #pragma unroll
      for (int nt = 0; nt < 8; ++nt)
        acc[nt] = __builtin_amdgcn_mfma_f32_16x16x32_bf16(
            fvs[ks], wb[((nt * 4 + ks) << 6) + lane], acc[nt], 0, 0, 0);
    }

    // dot: combine the 4 k-subgroups sharing row r
    float df = dot;
    df += __shfl_xor(df, 16);
    df += __shfl_xor(df, 32);
    const int h = mt * 16 + r;
    if (g == 0 && h < HLEN) dl[h] = df;

    // a[m] = sum over 128 cols of relu(Y+b)*w2
    float s0 = 0.f, s1 = 0.f, s2 = 0.f, s3 = 0.f;
    #pragma unroll
    for (int nt = 0; nt < 8; ++nt) {
      const int n = nt * 16 + r;
      const float bias = pb[n * 2];
      const float wv   = pb[n * 2 + 1];
      s0 += fmaxf(acc[nt].x + bias, 0.f) * wv;
      s1 += fmaxf(acc[nt].y + bias, 0.f) * wv;
      s2 += fmaxf(acc[nt].z + bias, 0.f) * wv;
      s3 += fmaxf(acc[nt].w + bias, 0.f) * wv;
    }
    #pragma unroll
    for (int m = 1; m <= 8; m <<= 1) {
      s0 += __shfl_xor(s0, m); s1 += __shfl_xor(s1, m);
      s2 += __shfl_xor(s2, m); s3 += __shfl_xor(s3, m);
    }
    if (r == 0) {
      const int base = mt * 16 + g * 4;
      a_arr[base + 0] = s0; a_arr[base + 1] = s1;
      a_arr[base + 2] = s2; a_arr[base + 3] = s3;
    }
  }

  __syncthreads();
  // branch-local epilogue: e = mask*exp(a+dist); S = sum e; P = sum e*dot
  float e = 0.f, p = 0.f;
  if (tid < HLEN) {
    const float dv  = tgt_dist[b * HLEN + tid] * SsumPtr[0];
    const float msk = (history[b * HLEN + tid] != target[b]) ? 1.f : 0.f;
    e = msk * expf(a_arr[tid] + dv);
    p = e * dl[tid];
  }
  #pragma unroll
  for (int m = 1; m <= 32; m <<= 1) {
    e += __shfl_xor(e, m);
    p += __shfl_xor(p, m);
  }
  if (lane == 0) { red[wg][0] = e; red[wg][1] = p; }
  __syncthreads();
  if (tid == 0) {
    const float S = red[0][0] + red[1][0] + red[2][0] + red[3][0];
    const float P = red[0][1] + red[1][1] + red[2][1] + red[3][1];
    const float c = P / sqrtf(S);
    // last-arriver combines the two branches and applies sigmoid
    __hip_atomic_store(&slots[br * B + b], c, __ATOMIC_RELAXED, __HIP_MEMORY_SCOPE_AGENT);
    const int t = __hip_atomic_fetch_add(&cnt[b], 1, __ATOMIC_ACQ_REL, __HIP_MEMORY_SCOPE_AGENT);
    if (t == 1) {
      const float o = __hip_atomic_load(&slots[(1 - br) * B + b], __ATOMIC_RELAXED, __HIP_MEMORY_SCOPE_AGENT);
      out[b] = 1.f / (1.f + expf(-(c + o)));
      __hip_atomic_store(&cnt[b], 0, __ATOMIC_RELAXED, __HIP_MEMORY_SCOPE_AGENT);
    }
  }
}

extern "C" void kernel_launch(void* const* d_in, const int* in_sizes, int n_in,
                              void* d_out, int out_size, void* d_ws, size_t ws_size,
                              hipStream_t stream) {
  const int*   history     = (const int*)d_in[0];
  const int*   target      = (const int*)d_in[1];
  const int*   hist_region = (const int*)d_in[2];
  const int*   tgt_region  = (const int*)d_in[3];
  const float* tgt_dist    = (const float*)d_in[4];
  const float* emb_hist    = (const float*)d_in[5];
  const float* emb_tgt     = (const float*)d_in[6];
  const float* emb_region  = (const float*)d_in[7];
  const float* emb_dist    = (const float*)d_in[8];
  const float* W1  = (const float*)d_in[9];
  const float* b1  = (const float*)d_in[10];
  const float* w2  = (const float*)d_in[11];
  const float* Wr1 = (const float*)d_in[12];
  const float* br1 = (const float*)d_in[13];
  const float* wr2 = (const float*)d_in[14];
  float* out = (float*)d_out;

  // workspace layout
  float* Sp    = (float*)d_ws;                          // 16 B slot
  float* slots = (float*)((char*)d_ws + 16);            // 2*B floats
  int*   cnt   = (int*)  ((char*)d_ws + 16 + 8192);     // B ints

  const int B = in_sizes[1];       // 1024
  hipLaunchKernelGGL(nais_prep, dim3(1), dim3(256), 0, stream,
                     emb_dist, Sp, cnt);
  hipLaunchKernelGGL(nais_main, dim3(2 * B), dim3(256), 0, stream,
                     history, target, hist_region, tgt_region, tgt_dist,
                     emb_hist, emb_tgt, emb_region,
                     W1, b1, w2, Wr1, br1, wr2, Sp, slots, cnt, out, B);
}

// Round 6
// 87.058 us; speedup vs baseline: 2.8851x; 1.0791x over previous
//
#include <hip/hip_runtime.h>
#include <hip/hip_bf16.h>
#include <math.h>

typedef __attribute__((ext_vector_type(4))) float f32x4;
typedef __attribute__((ext_vector_type(8))) __bf16 bf16x8;

#define HLEN 200
#define BATCH_MAX 1024

// ---------------------------------------------------------------------------
// prep kernel: build bf16 MFMA B-fragment tables for W1/Wr1 in workspace
// (global, 64 KB total), Ssum = sum(embed_distance[0][:]), zero counters.
// Fragment f = (nt*4+ks)*64+lane holds W[nt*16+(lane&15)][ks*32+(lane>>4)*8..+7].
// ---------------------------------------------------------------------------
__global__ __launch_bounds__(256)
void nais_prep(const float* __restrict__ W1, const float* __restrict__ Wr1,
               const float* __restrict__ emb_dist,
               __bf16* __restrict__ wfrag, float* __restrict__ Ssum,
               int* __restrict__ cnt)
{
  const int id = blockIdx.x * 256 + threadIdx.x;
  if (blockIdx.x < 16) {
    const float* W = (id < 2048) ? W1 : Wr1;
    const int f    = id & 2047;
    const int lane = f & 63;
    const int ks   = (f >> 6) & 3;
    const int nt   = f >> 8;
    const int n  = nt * 16 + (lane & 15);
    const int d0 = ks * 32 + (lane >> 4) * 8;
    const float* src = W + n * 128 + d0;
    bf16x8 p;
    #pragma unroll
    for (int e = 0; e < 8; ++e) p[e] = (__bf16)src[e];
    *(bf16x8*)&wfrag[(size_t)id * 8] = p;
  } else {
    if (threadIdx.x < 64) {
      float s = emb_dist[threadIdx.x] + emb_dist[threadIdx.x + 64];
      #pragma unroll
      for (int m = 32; m >= 1; m >>= 1) s += __shfl_xor(s, m);
      if (threadIdx.x == 0) Ssum[0] = s;
    }
    for (int k = threadIdx.x; k < BATCH_MAX; k += 256) cnt[k] = 0;
  }
}

// ---------------------------------------------------------------------------
// main kernel: grid = 2*B. Block = (batch row b, branch br); item blocks first.
// 512 threads = 8 WAVES (r5 post-mortem: plateau was wave-starvation at ~10
// waves/CU). Wave wg owns M-tiles mt = wg, wg+8 with full N=128 (acc[8]).
// LDS ~36 KB -> 4 blocks/CU x 8 waves = 32 waves/CU theoretical (needs
// VGPR <= 64; r5's identical loop body measured 60).
//  - W fragments pre-converted by prep (global table); per-block stage is a
//    pure coalesced 32 KB copy that OVERLAPS the t-gather (t no longer
//    folded into W — free, since the loop already computes q = x*t in f32
//    for the dot; fv now packs q instead of x).
//  - NO barriers in the loop; px prefetch 1 tile deep; anti-LICM zoff trick
//    keeps the 32 fragment reads in-loop (r3 spill lesson).
//  - epilogue cold loads (tgt_dist, history mask) prefetched into registers
//    at block start.
// ---------------------------------------------------------------------------
__global__ __launch_bounds__(512, 4)
void nais_main(const int* __restrict__ history, const int* __restrict__ target,
               const int* __restrict__ hist_region, const int* __restrict__ tgt_region,
               const float* __restrict__ tgt_dist,
               const float* __restrict__ emb_hist, const float* __restrict__ emb_tgt,
               const float* __restrict__ emb_region,
               const float* __restrict__ b1, const float* __restrict__ w2,
               const float* __restrict__ br1, const float* __restrict__ wr2,
               const __bf16* __restrict__ wfrag, const float* __restrict__ SsumPtr,
               float* __restrict__ slots, int* __restrict__ cnt,
               float* __restrict__ out, int B)
{
  __shared__ __align__(16) __bf16 wlds[16384];   // 32 KB fragment table
  __shared__ __align__(16) float tvec[128];
  __shared__ __align__(8)  float bw2[256];       // interleaved {bias,w2}
  __shared__ float a_arr[208];
  __shared__ float dl[208];
  __shared__ float red[8][2];

  const int tid  = threadIdx.x;
  const int lane = tid & 63;
  const int wg   = tid >> 6;    // 0..7
  const int r    = lane & 15;
  const int g    = lane >> 4;
  const int bid  = blockIdx.x;
  const int br   = (bid >= B) ? 1 : 0;
  const int b    = br ? (bid - B) : bid;

  const float* table  = br ? emb_region  : emb_hist;
  const int*   idxarr = br ? hist_region : history;

  // epilogue cold-load prefetch (issued first, consumed last)
  float td_pre = 0.f;
  int   hist_pre = 0;
  if (tid < HLEN) {
    td_pre   = tgt_dist[b * HLEN + tid];
    hist_pre = history[b * HLEN + tid];
  }
  const int   tgt_b = target[b];
  const float Ss    = SsumPtr[0];

  // W fragment stage: pure coalesced 32 KB copy (4 chunks/thread)
  {
    const bf16x8* src = (const bf16x8*)(wfrag + (size_t)br * 16384);
    #pragma unroll
    for (int i = 0; i < 4; ++i)
      *(bf16x8*)&wlds[(i * 512 + tid) * 8] = src[i * 512 + tid];
  }
  // t-vector + bias/w2 (overlaps the W copy)
  if (tid < 128) {
    const long trow = br ? (long)tgt_region[b] : (long)tgt_b;
    tvec[tid] = (br ? emb_region : emb_tgt)[trow * 128 + tid];
    bw2[tid * 2]     = (br ? br1 : b1)[tid];
    bw2[tid * 2 + 1] = (br ? wr2 : w2)[tid];
  }

  // gather prefetch: tile wg now, idx for tile wg+8
  int idx0;
  {
    const int h0 = wg * 16 + r;
    idx0 = (h0 < HLEN) ? idxarr[b * HLEN + h0] : 0;
  }
  f32x4 px[8];
  {
    const float* rowp = table + (long)idx0 * 128 + g * 8;
    #pragma unroll
    for (int ks = 0; ks < 4; ++ks) {
      px[2 * ks]     = *(const f32x4*)(rowp + ks * 32);
      px[2 * ks + 1] = *(const f32x4*)(rowp + ks * 32 + 4);
    }
  }
  int idxn;
  {
    const int tn = wg + 8;
    const int hn = tn * 16 + r;
    idxn = (tn < 13 && hn < HLEN) ? idxarr[b * HLEN + hn] : 0;
  }
  __syncthreads();   // wlds + tvec + bw2 ready — last barrier before epilogue

  #pragma unroll 1
  for (int mt = wg; mt < 13; mt += 8) {
    // opaque zero offset: LDS addresses become loop-variant -> LICM cannot
    // hoist the 32 fragment reads into (spilling) registers
    unsigned zoff = 0;
    asm volatile("" : "+v"(zoff));
    const bf16x8* wb = (const bf16x8*)wlds + zoff;
    const f32x4*  tb = (const f32x4*)tvec + zoff;
    const float*  pb = (const float*)bw2 + zoff;

    // q = x*t in f32 (dot needs it); fv = bf16(q) — A-fragment
    float dot = 0.f;
    bf16x8 fvs[4];
    #pragma unroll
    for (int ks = 0; ks < 4; ++ks) {
      const f32x4 x0 = px[2 * ks], x1 = px[2 * ks + 1];
      const f32x4 t0 = tb[ks * 8 + g * 2];
      const f32x4 t1 = tb[ks * 8 + g * 2 + 1];
      const f32x4 q0 = x0 * t0;
      const f32x4 q1 = x1 * t1;
      dot += ((q0.x + q0.y) + (q0.z + q0.w)) + ((q1.x + q1.y) + (q1.z + q1.w));
      bf16x8 fv;
      fv[0] = (__bf16)q0.x; fv[1] = (__bf16)q0.y; fv[2] = (__bf16)q0.z; fv[3] = (__bf16)q0.w;
      fv[4] = (__bf16)q1.x; fv[5] = (__bf16)q1.y; fv[6] = (__bf16)q1.z; fv[7] = (__bf16)q1.w;
      fvs[ks] = fv;
    }

    // px dead: issue next tile's gather (only if a next tile exists)
    if (mt + 8 < 13) {
      const float* rowp = table + (long)idxn * 128 + g * 8;
      #pragma unroll
      for (int ks = 0; ks < 4; ++ks) {
        px[2 * ks]     = *(const f32x4*)(rowp + ks * 32);
        px[2 * ks + 1] = *(const f32x4*)(rowp + ks * 32 + 4);
      }
    }

    // GEMM tile: 32 MFMA, B-fragments from LDS (conflict-free layout)
    f32x4 acc[8];
    #pragma unroll
    for (int nt = 0; nt < 8; ++nt) acc[nt] = (f32x4){0.f, 0.f, 0.f, 0.f};
    #pragma unroll
    for (int ks = 0; ks < 4; ++ks) {
      #pragma unroll
      for (int nt = 0; nt < 8; ++nt)
        acc[nt] = __builtin_amdgcn_mfma_f32_16x16x32_bf16(
            fvs[ks], wb[((nt * 4 + ks) << 6) + lane], acc[nt], 0, 0, 0);
    }

    // dot: combine the 4 k-subgroups sharing row r
    float df = dot;
    df += __shfl_xor(df, 16);
    df += __shfl_xor(df, 32);
    const int h = mt * 16 + r;
    if (g == 0 && h < HLEN) dl[h] = df;

    // a[m] = sum over 128 cols of relu(Y+b)*w2
    float s0 = 0.f, s1 = 0.f, s2 = 0.f, s3 = 0.f;
    #pragma unroll
    for (int nt = 0; nt < 8; ++nt) {
      const int n = nt * 16 + r;
      const float bias = pb[n * 2];
      const float wv   = pb[n * 2 + 1];
      s0 += fmaxf(acc[nt].x + bias, 0.f) * wv;
      s1 += fmaxf(acc[nt].y + bias, 0.f) * wv;
      s2 += fmaxf(acc[nt].z + bias, 0.f) * wv;
      s3 += fmaxf(acc[nt].w + bias, 0.f) * wv;
    }
    #pragma unroll
    for (int m = 1; m <= 8; m <<= 1) {
      s0 += __shfl_xor(s0, m); s1 += __shfl_xor(s1, m);
      s2 += __shfl_xor(s2, m); s3 += __shfl_xor(s3, m);
    }
    if (r == 0) {
      const int base = mt * 16 + g * 4;
      a_arr[base + 0] = s0; a_arr[base + 1] = s1;
      a_arr[base + 2] = s2; a_arr[base + 3] = s3;
    }
  }

  __syncthreads();
  // branch-local epilogue: e = mask*exp(a+dist); S = sum e; P = sum e*dot
  float e = 0.f, p = 0.f;
  if (tid < HLEN) {
    const float dv  = td_pre * Ss;
    const float msk = (hist_pre != tgt_b) ? 1.f : 0.f;
    e = msk * expf(a_arr[tid] + dv);
    p = e * dl[tid];
  }
  #pragma unroll
  for (int m = 1; m <= 32; m <<= 1) {
    e += __shfl_xor(e, m);
    p += __shfl_xor(p, m);
  }
  if (lane == 0) { red[wg][0] = e; red[wg][1] = p; }
  __syncthreads();
  if (tid == 0) {
    float S = 0.f, P = 0.f;
    #pragma unroll
    for (int w = 0; w < 8; ++w) { S += red[w][0]; P += red[w][1]; }
    const float c = P / sqrtf(S);
    // last-arriver combines the two branches and applies sigmoid
    __hip_atomic_store(&slots[br * B + b], c, __ATOMIC_RELAXED, __HIP_MEMORY_SCOPE_AGENT);
    const int t = __hip_atomic_fetch_add(&cnt[b], 1, __ATOMIC_ACQ_REL, __HIP_MEMORY_SCOPE_AGENT);
    if (t == 1) {
      const float o = __hip_atomic_load(&slots[(1 - br) * B + b], __ATOMIC_RELAXED, __HIP_MEMORY_SCOPE_AGENT);
      out[b] = 1.f / (1.f + expf(-(c + o)));
      __hip_atomic_store(&cnt[b], 0, __ATOMIC_RELAXED, __HIP_MEMORY_SCOPE_AGENT);
    }
  }
}

extern "C" void kernel_launch(void* const* d_in, const int* in_sizes, int n_in,
                              void* d_out, int out_size, void* d_ws, size_t ws_size,
                              hipStream_t stream) {
  const int*   history     = (const int*)d_in[0];
  const int*   target      = (const int*)d_in[1];
  const int*   hist_region = (const int*)d_in[2];
  const int*   tgt_region  = (const int*)d_in[3];
  const float* tgt_dist    = (const float*)d_in[4];
  const float* emb_hist    = (const float*)d_in[5];
  const float* emb_tgt     = (const float*)d_in[6];
  const float* emb_region  = (const float*)d_in[7];
  const float* emb_dist    = (const float*)d_in[8];
  const float* W1  = (const float*)d_in[9];
  const float* b1  = (const float*)d_in[10];
  const float* w2  = (const float*)d_in[11];
  const float* Wr1 = (const float*)d_in[12];
  const float* br1 = (const float*)d_in[13];
  const float* wr2 = (const float*)d_in[14];
  float* out = (float*)d_out;

  // workspace layout
  __bf16* wfrag = (__bf16*)d_ws;                          // 65536 B
  float*  Sp    = (float*)((char*)d_ws + 65536);          // 16 B slot
  float*  slots = (float*)((char*)d_ws + 65552);          // 2*B floats
  int*    cnt   = (int*)  ((char*)d_ws + 65552 + 8192);   // B ints

  const int B = in_sizes[1];       // 1024
  hipLaunchKernelGGL(nais_prep, dim3(17), dim3(256), 0, stream,
                     W1, Wr1, emb_dist, wfrag, Sp, cnt);
  hipLaunchKernelGGL(nais_main, dim3(2 * B), dim3(512), 0, stream,
                     history, target, hist_region, tgt_region, tgt_dist,
                     emb_hist, emb_tgt, emb_region,
                     b1, w2, br1, wr2, wfrag, Sp, slots, cnt, out, B);
}

// Round 7
// 72.151 us; speedup vs baseline: 3.4812x; 1.2066x over previous
//
#include <hip/hip_runtime.h>
#include <hip/hip_bf16.h>
#include <math.h>

typedef __attribute__((ext_vector_type(4))) float f32x4;
typedef __attribute__((ext_vector_type(8))) __bf16 bf16x8;

#define HLEN 200
#define BATCH_MAX 1024

// ---------------------------------------------------------------------------
// prep kernel: build bf16 MFMA B-fragment tables for W1/Wr1 in workspace
// (global, 64 KB total), Ssum = sum(embed_distance[0][:]), zero counters.
// Fragment f = (nt*4+ks)*64+lane holds W[nt*16+(lane&15)][ks*32+(lane>>4)*8..+7].
// ---------------------------------------------------------------------------
__global__ __launch_bounds__(256)
void nais_prep(const float* __restrict__ W1, const float* __restrict__ Wr1,
               const float* __restrict__ emb_dist,
               __bf16* __restrict__ wfrag, float* __restrict__ Ssum,
               int* __restrict__ cnt)
{
  const int id = blockIdx.x * 256 + threadIdx.x;
  if (blockIdx.x < 16) {
    const float* W = (id < 2048) ? W1 : Wr1;
    const int f    = id & 2047;
    const int lane = f & 63;
    const int ks   = (f >> 6) & 3;
    const int nt   = f >> 8;
    const int n  = nt * 16 + (lane & 15);
    const int d0 = ks * 32 + (lane >> 4) * 8;
    const float* src = W + n * 128 + d0;
    bf16x8 p;
    #pragma unroll
    for (int e = 0; e < 8; ++e) p[e] = (__bf16)src[e];
    *(bf16x8*)&wfrag[(size_t)id * 8] = p;
  } else {
    if (threadIdx.x < 64) {
      float s = emb_dist[threadIdx.x] + emb_dist[threadIdx.x + 64];
      #pragma unroll
      for (int m = 32; m >= 1; m >>= 1) s += __shfl_xor(s, m);
      if (threadIdx.x == 0) Ssum[0] = s;
    }
    for (int k = threadIdx.x; k < BATCH_MAX; k += 256) cnt[k] = 0;
  }
}

// ---------------------------------------------------------------------------
// main kernel: ONE SAMPLE PER WAVE (r6 post-mortem: occupancy is capped at
// 16 waves/CU by the ~100-unified-reg footprint; the lever is per-wave MLP).
// grid = 2*(B/4): block = 4 waves = 4 samples, branch-uniform (item blocks
// first). Each wave runs all 13 M-tiles of its sample -> the 1-deep px
// prefetch hides gather latency for 12/13 tiles, keeping a ~128-cache-line
// miss batch continuously in flight per wave (goal: the 2 TB/s random-gather
// rate r2 demonstrated, on r6's minimal 51 MB footprint).
//  - W fragments from prep's global table; 32 KB coalesced LDS copy.
//  - zoff anti-LICM keeps the 32 in-loop fragment reads in LDS (r3 lesson).
//  - NO barrier in or after the loop: a/d arrays are wave-private (LDS[wg]),
//    epilogue is a pure 64-lane reduction + device-scope ticket.
// ---------------------------------------------------------------------------
__global__ __launch_bounds__(256, 4)
void nais_main(const int* __restrict__ history, const int* __restrict__ target,
               const int* __restrict__ hist_region, const int* __restrict__ tgt_region,
               const float* __restrict__ tgt_dist,
               const float* __restrict__ emb_hist, const float* __restrict__ emb_tgt,
               const float* __restrict__ emb_region,
               const float* __restrict__ b1, const float* __restrict__ w2,
               const float* __restrict__ br1, const float* __restrict__ wr2,
               const __bf16* __restrict__ wfrag, const float* __restrict__ SsumPtr,
               float* __restrict__ slots, int* __restrict__ cnt,
               float* __restrict__ out, int B)
{
  __shared__ __align__(16) __bf16 wlds[16384];   // 32 KB fragment table
  __shared__ __align__(16) float tvec4[4][128];  // per-wave t-vector
  __shared__ __align__(8)  float bw2[256];       // interleaved {bias,w2}
  __shared__ float aarr[4][208];                 // per-wave a[h]
  __shared__ float dlarr[4][208];                // per-wave dot[h]

  const int tid  = threadIdx.x;
  const int lane = tid & 63;
  const int wg   = tid >> 6;    // wave = sample slot 0..3
  const int r    = lane & 15;
  const int g    = lane >> 4;
  const int bid  = blockIdx.x;
  const int GB   = B >> 2;      // blocks per branch
  const int br   = (bid >= GB) ? 1 : 0;
  const int s    = (br ? bid - GB : bid) * 4 + wg;   // this wave's sample

  const float* table  = br ? emb_region  : emb_hist;
  const int*   idxarr = br ? hist_region : history;

  // scalar hoists (consumed in epilogue too)
  const int   tgt_s = target[s];
  const float Ss    = SsumPtr[0];

  // W fragment stage: pure coalesced 32 KB copy (8 chunks/thread)
  {
    const bf16x8* src = (const bf16x8*)(wfrag + (size_t)br * 16384);
    #pragma unroll
    for (int i = 0; i < 8; ++i)
      *(bf16x8*)&wlds[(i * 256 + tid) * 8] = src[i * 256 + tid];
  }
  if (tid < 128) {
    bw2[tid * 2]     = (br ? br1 : b1)[tid];
    bw2[tid * 2 + 1] = (br ? wr2 : w2)[tid];
  }
  // per-wave t-vector (written and read by the same wave)
  {
    const long trow = br ? (long)tgt_region[s] : (long)tgt_s;
    const float* tsrc = (br ? emb_region : emb_tgt) + trow * 128;
    tvec4[wg][lane]      = tsrc[lane];
    tvec4[wg][lane + 64] = tsrc[lane + 64];
  }

  // gather prefetch: tile 0 rows now, idx for tile 1
  f32x4 px[8];
  {
    const int i0 = idxarr[s * HLEN + r];          // h = r < 200 always valid
    const float* rowp = table + (long)i0 * 128 + g * 8;
    #pragma unroll
    for (int ks = 0; ks < 4; ++ks) {
      px[2 * ks]     = *(const f32x4*)(rowp + ks * 32);
      px[2 * ks + 1] = *(const f32x4*)(rowp + ks * 32 + 4);
    }
  }
  int idn = idxarr[s * HLEN + 16 + r];            // tile 1, h = 16+r < 200
  __syncthreads();   // wlds + bw2 ready — the ONLY barrier in this kernel

  #pragma unroll 1
  for (int mt = 0; mt < 13; ++mt) {
    // opaque zero offset: LDS addresses become loop-variant -> LICM cannot
    // hoist the 32 fragment reads into (spilling) registers
    unsigned zoff = 0;
    asm volatile("" : "+v"(zoff));
    const bf16x8* wb = (const bf16x8*)wlds + zoff;
    const f32x4*  tb = (const f32x4*)tvec4[wg] + zoff;
    const float*  pb = (const float*)bw2 + zoff;

    // q = x*t in f32 (dot needs it); fv = bf16(q) — A-fragment
    float dot = 0.f;
    bf16x8 fvs[4];
    #pragma unroll
    for (int ks = 0; ks < 4; ++ks) {
      const f32x4 x0 = px[2 * ks], x1 = px[2 * ks + 1];
      const f32x4 t0 = tb[ks * 8 + g * 2];
      const f32x4 t1 = tb[ks * 8 + g * 2 + 1];
      const f32x4 q0 = x0 * t0;
      const f32x4 q1 = x1 * t1;
      dot += ((q0.x + q0.y) + (q0.z + q0.w)) + ((q1.x + q1.y) + (q1.z + q1.w));
      bf16x8 fv;
      fv[0] = (__bf16)q0.x; fv[1] = (__bf16)q0.y; fv[2] = (__bf16)q0.z; fv[3] = (__bf16)q0.w;
      fv[4] = (__bf16)q1.x; fv[5] = (__bf16)q1.y; fv[6] = (__bf16)q1.z; fv[7] = (__bf16)q1.w;
      fvs[ks] = fv;
    }

    // px dead: issue next tile's gather + idx for tile mt+2
    if (mt < 12) {
      const float* rowp = table + (long)idn * 128 + g * 8;
      #pragma unroll
      for (int ks = 0; ks < 4; ++ks) {
        px[2 * ks]     = *(const f32x4*)(rowp + ks * 32);
        px[2 * ks + 1] = *(const f32x4*)(rowp + ks * 32 + 4);
      }
      const int tn = mt + 2;
      const int hn = tn * 16 + r;
      idn = (tn < 13 && hn < HLEN) ? idxarr[s * HLEN + hn] : 0;
    }

    // GEMM tile: 32 MFMA, B-fragments from LDS (conflict-free layout)
    f32x4 acc[8];
    #pragma unroll
    for (int nt = 0; nt < 8; ++nt) acc[nt] = (f32x4){0.f, 0.f, 0.f, 0.f};
    #pragma unroll
    for (int ks = 0; ks < 4; ++ks) {
      #pragma unroll
      for (int nt = 0; nt < 8; ++nt)
        acc[nt] = __builtin_amdgcn_mfma_f32_16x16x32_bf16(
            fvs[ks], wb[((nt * 4 + ks) << 6) + lane], acc[nt], 0, 0, 0);
    }

    // dot: combine the 4 k-subgroups sharing row r
    float df = dot;
    df += __shfl_xor(df, 16);
    df += __shfl_xor(df, 32);
    const int h = mt * 16 + r;
    if (g == 0 && h < HLEN) dlarr[wg][h] = df;

    // a[m] = sum over 128 cols of relu(Y+b)*w2
    float s0 = 0.f, s1 = 0.f, s2 = 0.f, s3 = 0.f;
    #pragma unroll
    for (int nt = 0; nt < 8; ++nt) {
      const int n = nt * 16 + r;
      const float bias = pb[n * 2];
      const float wv   = pb[n * 2 + 1];
      s0 += fmaxf(acc[nt].x + bias, 0.f) * wv;
      s1 += fmaxf(acc[nt].y + bias, 0.f) * wv;
      s2 += fmaxf(acc[nt].z + bias, 0.f) * wv;
      s3 += fmaxf(acc[nt].w + bias, 0.f) * wv;
    }
    #pragma unroll
    for (int m = 1; m <= 8; m <<= 1) {
      s0 += __shfl_xor(s0, m); s1 += __shfl_xor(s1, m);
      s2 += __shfl_xor(s2, m); s3 += __shfl_xor(s3, m);
    }
    if (r == 0) {
      const int base = mt * 16 + g * 4;
      aarr[wg][base + 0] = s0; aarr[wg][base + 1] = s1;
      aarr[wg][base + 2] = s2; aarr[wg][base + 3] = s3;
    }
  }

  // wave-private epilogue (no barrier): each lane covers h = lane + 64q
  float e = 0.f, p = 0.f;
  #pragma unroll
  for (int q = 0; q < 4; ++q) {
    const int h = lane + q * 64;
    if (h < HLEN) {
      const float dv  = tgt_dist[s * HLEN + h] * Ss;
      const float msk = (history[s * HLEN + h] != tgt_s) ? 1.f : 0.f;
      const float ee  = msk * expf(aarr[wg][h] + dv);
      e += ee;
      p += ee * dlarr[wg][h];
    }
  }
  #pragma unroll
  for (int m = 1; m <= 32; m <<= 1) {
    e += __shfl_xor(e, m);
    p += __shfl_xor(p, m);
  }
  if (lane == 0) {
    const float c = p / sqrtf(e);
    // last-arriver combines the two branches and applies sigmoid
    __hip_atomic_store(&slots[br * B + s], c, __ATOMIC_RELAXED, __HIP_MEMORY_SCOPE_AGENT);
    const int t = __hip_atomic_fetch_add(&cnt[s], 1, __ATOMIC_ACQ_REL, __HIP_MEMORY_SCOPE_AGENT);
    if (t == 1) {
      const float o = __hip_atomic_load(&slots[(1 - br) * B + s], __ATOMIC_RELAXED, __HIP_MEMORY_SCOPE_AGENT);
      out[s] = 1.f / (1.f + expf(-(c + o)));
      __hip_atomic_store(&cnt[s], 0, __ATOMIC_RELAXED, __HIP_MEMORY_SCOPE_AGENT);
    }
  }
}

extern "C" void kernel_launch(void* const* d_in, const int* in_sizes, int n_in,
                              void* d_out, int out_size, void* d_ws, size_t ws_size,
                              hipStream_t stream) {
  const int*   history     = (const int*)d_in[0];
  const int*   target      = (const int*)d_in[1];
  const int*   hist_region = (const int*)d_in[2];
  const int*   tgt_region  = (const int*)d_in[3];
  const float* tgt_dist    = (const float*)d_in[4];
  const float* emb_hist    = (const float*)d_in[5];
  const float* emb_tgt     = (const float*)d_in[6];
  const float* emb_region  = (const float*)d_in[7];
  const float* emb_dist    = (const float*)d_in[8];
  const float* W1  = (const float*)d_in[9];
  const float* b1  = (const float*)d_in[10];
  const float* w2  = (const float*)d_in[11];
  const float* Wr1 = (const float*)d_in[12];
  const float* br1 = (const float*)d_in[13];
  const float* wr2 = (const float*)d_in[14];
  float* out = (float*)d_out;

  // workspace layout
  __bf16* wfrag = (__bf16*)d_ws;                          // 65536 B
  float*  Sp    = (float*)((char*)d_ws + 65536);          // 16 B slot
  float*  slots = (float*)((char*)d_ws + 65552);          // 2*B floats
  int*    cnt   = (int*)  ((char*)d_ws + 65552 + 8192);   // B ints

  const int B = in_sizes[1];       // 1024
  hipLaunchKernelGGL(nais_prep, dim3(17), dim3(256), 0, stream,
                     W1, Wr1, emb_dist, wfrag, Sp, cnt);
  hipLaunchKernelGGL(nais_main, dim3(2 * (B / 4)), dim3(256), 0, stream,
                     history, target, hist_region, tgt_region, tgt_dist,
                     emb_hist, emb_tgt, emb_region,
                     b1, w2, br1, wr2, wfrag, Sp, slots, cnt, out, B);
}